// Round 2
// baseline (158.699 us; speedup 1.0000x reference)
//
#include <hip/hip_runtime.h>

// SymmetryControl: B=16, C=96, H=96, W=96 fp32.
// out[b,c,h,i] = num/den, 6 taps of the same 96-wide row, gated by sigmoid(s[b,:]).
//
// R6 theory: R4/R5 were latency-bound on the LDS round-trip + block-wide barrier
// (no pipe >30%). The row-local gather doesn't need LDS at all: map one row to
// 32 lanes x 3 floats (96 = 32*3; 32 | 64 -> 2 rows per wave). Every tap is then
// a STATIC lane permutation within a 32-lane half:
//   col i = 3*tl + e
//   shift -24: lane (tl-8)&31,  same elem      (i-24 = 3*(tl-8)+e)
//   shift -48: lane (tl-16)&31, same elem
//   shift -72: lane (tl+8)&31,  same elem
//   flip 23-i: lane (7-tl)&31,  elem reversed  (23-i = 3*((7-tl)&31)+(2-e))
//   flip 47-i: lane (15-tl)&31, elem reversed
// ds_bpermute does the redistribution in-register: no LDS buffer, no barrier,
// no bank conflicts, waves fully independent. 1-deep register prefetch hides
// HBM latency; occupancy limited only by VGPRs.

#define WDIM 96
#define RPB  9216            // rows per batch (C*H)
#define QPB  (RPB / 2)       // row-pairs per batch = 4608
#define WPB  4               // waves per block (256 threads)
#define GRID 2048            // 8192 waves -> span = 73728/8192 = 9 iters/wave

__device__ __forceinline__ float bperm(int byteidx, float v) {
    return __int_as_float(__builtin_amdgcn_ds_bpermute(byteidx, __float_as_int(v)));
}

__global__ __launch_bounds__(64 * WPB)
void symctl_kernel(const float* __restrict__ x,
                   const float* __restrict__ s,
                   const float* __restrict__ w,
                   float* __restrict__ out,
                   int total_q) {
    const int lane = threadIdx.x & 63;
    const int tl   = lane & 31;          // position within 32-lane half
    const int hsel = lane & 32;          // half selector (0 / 32)
    const int h    = lane >> 5;          // row parity within the pair

    const int gw = blockIdx.x * WPB + (threadIdx.x >> 6);   // global wave id
    const int nw = gridDim.x * WPB;

    // contiguous span of row-pairs per wave (keeps batch index nearly constant)
    const int span = (total_q + nw - 1) / nw;
    const int q0 = gw * span;
    const int q1 = min(q0 + span, total_q);
    if (q0 >= q1) return;                // whole-wave uniform exit

    // bpermute byte indices (per-lane constants, stay within own 32-lane half)
    const int i90  = (hsel | ((tl -  8) & 31)) << 2;
    const int i180 = (hsel | ((tl - 16) & 31)) << 2;
    const int i270 = (hsel | ((tl +  8) & 31)) << 2;
    const int f90  = (hsel | (( 7 - tl) & 31)) << 2;
    const int f180 = (hsel | ((15 - tl) & 31)) << 2;

    int bcur = -1;
    float sg0 = 0.f, sg1 = 0.f, sg2 = 0.f, sg3 = 0.f, sg4 = 0.f;

    // prologue prefetch
    size_t off = (size_t)(2 * q0 + h) * WDIM + 3 * tl;
    float3 xv = *(const float3*)(x + off);
    float3 wv = *(const float3*)(w + off);

    for (int q = q0; q < q1; ++q) {
        const float3 xc = xv;
        const float3 wc = wv;

        // prefetch next row-pair (independent loads, hide HBM latency)
        if (q + 1 < q1) {
            const size_t noff = (size_t)(2 * (q + 1) + h) * WDIM + 3 * tl;
            xv = *(const float3*)(x + noff);
            wv = *(const float3*)(w + noff);
        }

        // per-batch sigmoid gates (wave-uniform branch, taken ~once per wave)
        const int b = q / QPB;
        if (b != bcur) {
            bcur = b;
            const float* sb = s + b * 5;
            sg0 = 1.0f / (1.0f + __expf(-sb[0]));
            sg1 = 1.0f / (1.0f + __expf(-sb[1]));
            sg2 = 1.0f / (1.0f + __expf(-sb[2]));
            sg3 = 1.0f / (1.0f + __expf(-sb[3]));
            sg4 = 1.0f / (1.0f + __expf(-sb[4]));
        }

        const float p0 = xc.x * wc.x;
        const float p1 = xc.y * wc.y;
        const float p2 = xc.z * wc.z;

        float n0 = p0,   n1 = p1,   n2 = p2;
        float d0 = wc.x, d1 = wc.y, d2 = wc.z;

        // ---- shift taps: same element, shuffled lane ----
        n0 = fmaf(sg0, bperm(i90,  p0),   n0);
        n1 = fmaf(sg0, bperm(i90,  p1),   n1);
        n2 = fmaf(sg0, bperm(i90,  p2),   n2);
        d0 = fmaf(sg0, bperm(i90,  wc.x), d0);
        d1 = fmaf(sg0, bperm(i90,  wc.y), d1);
        d2 = fmaf(sg0, bperm(i90,  wc.z), d2);

        n0 = fmaf(sg1, bperm(i180, p0),   n0);
        n1 = fmaf(sg1, bperm(i180, p1),   n1);
        n2 = fmaf(sg1, bperm(i180, p2),   n2);
        d0 = fmaf(sg1, bperm(i180, wc.x), d0);
        d1 = fmaf(sg1, bperm(i180, wc.y), d1);
        d2 = fmaf(sg1, bperm(i180, wc.z), d2);

        n0 = fmaf(sg2, bperm(i270, p0),   n0);
        n1 = fmaf(sg2, bperm(i270, p1),   n1);
        n2 = fmaf(sg2, bperm(i270, p2),   n2);
        d0 = fmaf(sg2, bperm(i270, wc.x), d0);
        d1 = fmaf(sg2, bperm(i270, wc.y), d1);
        d2 = fmaf(sg2, bperm(i270, wc.z), d2);

        // ---- flip taps: shuffled lane, elements reversed (out e <- src 2-e) ----
        n0 = fmaf(sg3, bperm(f90,  p2),   n0);
        n1 = fmaf(sg3, bperm(f90,  p1),   n1);
        n2 = fmaf(sg3, bperm(f90,  p0),   n2);
        d0 = fmaf(sg3, bperm(f90,  wc.z), d0);
        d1 = fmaf(sg3, bperm(f90,  wc.y), d1);
        d2 = fmaf(sg3, bperm(f90,  wc.x), d2);

        n0 = fmaf(sg4, bperm(f180, p2),   n0);
        n1 = fmaf(sg4, bperm(f180, p1),   n1);
        n2 = fmaf(sg4, bperm(f180, p0),   n2);
        d0 = fmaf(sg4, bperm(f180, wc.z), d0);
        d1 = fmaf(sg4, bperm(f180, wc.y), d1);
        d2 = fmaf(sg4, bperm(f180, wc.x), d2);

        float3 o;
        o.x = n0 * __builtin_amdgcn_rcpf(d0);
        o.y = n1 * __builtin_amdgcn_rcpf(d1);
        o.z = n2 * __builtin_amdgcn_rcpf(d2);
        *(float3*)(out + (size_t)(2 * q + h) * WDIM + 3 * tl) = o;
    }
}

extern "C" void kernel_launch(void* const* d_in, const int* in_sizes, int n_in,
                              void* d_out, int out_size, void* d_ws, size_t ws_size,
                              hipStream_t stream) {
    const float* x = (const float*)d_in[0];
    const float* s = (const float*)d_in[1];
    const float* w = (const float*)d_in[2];
    float* out = (float*)d_out;

    const int n_rows  = in_sizes[0] / WDIM;   // 147456 (in_sizes[0] = float count)
    const int total_q = n_rows / 2;           // 73728 row-pairs

    const int waves_needed = total_q;         // upper bound
    int grid = GRID;
    if (grid * WPB > waves_needed) grid = (waves_needed + WPB - 1) / WPB;

    dim3 block(64 * WPB);
    symctl_kernel<<<grid, block, 0, stream>>>(x, s, w, out, total_q);
}

// Round 3
// 153.272 us; speedup vs baseline: 1.0354x; 1.0354x over previous
//
#include <hip/hip_runtime.h>

// SymmetryControl: B=16, C=96, H=96, W=96 fp32.
// out[b,c,h,i] = num/den, 6 taps of the same 96-wide row, gated by sigmoid(s[b,:]).
//
// R7 theory: R4/R5/R6 (three different structures) all plateau at 2.0-2.3 TB/s
// with VALUBusy <26% and zero conflicts -> not sync, not LDS. The invariant was
// a 1-deep pipeline: ~2 loads (1.5 KB) in flight per wave, then a vmcnt stall of
// ~1000+ cyc. Memory-level parallelism was the limiter. Fix: ONE-SHOT waves.
// Each wave = 4 row-pairs (8 rows): issue all 8 contiguous 768B loads
// back-to-back (6 KB in flight/wave, ~32 waves/CU -> queues fill), then consume
// pair-by-pair; the compiler's per-pair vmcnt(6)/(4)/(2) waits mean only the
// first pair ever stalls. Sigmoid gates are block-uniform (32 rows/block) so
// s[] goes down the scalar SMEM path and never touches the vector queue.
// Row->lane map (verified in R6): row = 32 lanes x 3 floats, 2 rows/wave:
//   col i = 3*tl + e
//   shift -24: lane (tl-8)&31,  same elem
//   shift -48: lane (tl-16)&31, same elem
//   shift -72: lane (tl+8)&31,  same elem
//   flip 23-i: lane (7-tl)&31,  elems reversed
//   flip 47-i: lane (15-tl)&31, elems reversed

#define WDIM 96
#define RPB  9216            // rows per batch (C*H)
#define WPB  4               // waves per block (256 threads)
#define RPW  8               // rows per wave (4 row-pairs, one-shot)

__device__ __forceinline__ float bperm(int byteidx, float v) {
    return __int_as_float(__builtin_amdgcn_ds_bpermute(byteidx, __float_as_int(v)));
}

__global__ __launch_bounds__(64 * WPB)
void symctl_kernel(const float* __restrict__ x,
                   const float* __restrict__ s,
                   const float* __restrict__ w,
                   float* __restrict__ out) {
    const int lane = threadIdx.x & 63;
    const int tl   = lane & 31;          // position within 32-lane half
    const int hsel = lane & 32;          // half selector (0 / 32)
    const int h    = lane >> 5;          // row parity within each pair

    const int wid = blockIdx.x * WPB + (threadIdx.x >> 6);   // global wave id
    // wave covers rows 8*wid .. 8*wid+7; lane handles rows 8*wid + 2k + h
    const int base = (RPW * wid + h) * WDIM + 3 * tl;        // fits 32-bit

    // ---- issue ALL 8 loads back-to-back (6 KB in flight per wave) ----
    float3 xa[4], wa[4];
#pragma unroll
    for (int k = 0; k < 4; ++k)
        xa[k] = *(const float3*)(x + base + k * (2 * WDIM));
#pragma unroll
    for (int k = 0; k < 4; ++k)
        wa[k] = *(const float3*)(w + base + k * (2 * WDIM));

    // ---- block-uniform sigmoid gates (scalar SMEM path, no vmcnt traffic) ----
    const int b = (blockIdx.x * (RPW * WPB)) / RPB;          // block-uniform
    const float* sb = s + b * 5;
    const float sg0 = 1.0f / (1.0f + __expf(-sb[0]));
    const float sg1 = 1.0f / (1.0f + __expf(-sb[1]));
    const float sg2 = 1.0f / (1.0f + __expf(-sb[2]));
    const float sg3 = 1.0f / (1.0f + __expf(-sb[3]));
    const float sg4 = 1.0f / (1.0f + __expf(-sb[4]));

    // bpermute byte indices (per-lane constants, stay within own 32-lane half)
    const int i90  = (hsel | ((tl -  8) & 31)) << 2;
    const int i180 = (hsel | ((tl - 16) & 31)) << 2;
    const int i270 = (hsel | ((tl +  8) & 31)) << 2;
    const int f90  = (hsel | (( 7 - tl) & 31)) << 2;
    const int f180 = (hsel | ((15 - tl) & 31)) << 2;

#pragma unroll
    for (int k = 0; k < 4; ++k) {
        const float3 xc = xa[k];
        const float3 wc = wa[k];

        const float p0 = xc.x * wc.x;
        const float p1 = xc.y * wc.y;
        const float p2 = xc.z * wc.z;

        float n0 = p0,   n1 = p1,   n2 = p2;
        float d0 = wc.x, d1 = wc.y, d2 = wc.z;

        // ---- shift taps: same element, shuffled lane ----
        n0 = fmaf(sg0, bperm(i90,  p0),   n0);
        n1 = fmaf(sg0, bperm(i90,  p1),   n1);
        n2 = fmaf(sg0, bperm(i90,  p2),   n2);
        d0 = fmaf(sg0, bperm(i90,  wc.x), d0);
        d1 = fmaf(sg0, bperm(i90,  wc.y), d1);
        d2 = fmaf(sg0, bperm(i90,  wc.z), d2);

        n0 = fmaf(sg1, bperm(i180, p0),   n0);
        n1 = fmaf(sg1, bperm(i180, p1),   n1);
        n2 = fmaf(sg1, bperm(i180, p2),   n2);
        d0 = fmaf(sg1, bperm(i180, wc.x), d0);
        d1 = fmaf(sg1, bperm(i180, wc.y), d1);
        d2 = fmaf(sg1, bperm(i180, wc.z), d2);

        n0 = fmaf(sg2, bperm(i270, p0),   n0);
        n1 = fmaf(sg2, bperm(i270, p1),   n1);
        n2 = fmaf(sg2, bperm(i270, p2),   n2);
        d0 = fmaf(sg2, bperm(i270, wc.x), d0);
        d1 = fmaf(sg2, bperm(i270, wc.y), d1);
        d2 = fmaf(sg2, bperm(i270, wc.z), d2);

        // ---- flip taps: shuffled lane, elements reversed (out e <- src 2-e) ----
        n0 = fmaf(sg3, bperm(f90,  p2),   n0);
        n1 = fmaf(sg3, bperm(f90,  p1),   n1);
        n2 = fmaf(sg3, bperm(f90,  p0),   n2);
        d0 = fmaf(sg3, bperm(f90,  wc.z), d0);
        d1 = fmaf(sg3, bperm(f90,  wc.y), d1);
        d2 = fmaf(sg3, bperm(f90,  wc.x), d2);

        n0 = fmaf(sg4, bperm(f180, p2),   n0);
        n1 = fmaf(sg4, bperm(f180, p1),   n1);
        n2 = fmaf(sg4, bperm(f180, p0),   n2);
        d0 = fmaf(sg4, bperm(f180, wc.z), d0);
        d1 = fmaf(sg4, bperm(f180, wc.y), d1);
        d2 = fmaf(sg4, bperm(f180, wc.x), d2);

        float3 o;
        o.x = n0 * __builtin_amdgcn_rcpf(d0);
        o.y = n1 * __builtin_amdgcn_rcpf(d1);
        o.z = n2 * __builtin_amdgcn_rcpf(d2);
        *(float3*)(out + base + k * (2 * WDIM)) = o;
    }
}

extern "C" void kernel_launch(void* const* d_in, const int* in_sizes, int n_in,
                              void* d_out, int out_size, void* d_ws, size_t ws_size,
                              hipStream_t stream) {
    const float* x = (const float*)d_in[0];
    const float* s = (const float*)d_in[1];
    const float* w = (const float*)d_in[2];
    float* out = (float*)d_out;

    const int n_rows = in_sizes[0] / WDIM;        // 147456 (in_sizes[0] = float count)
    const int waves  = n_rows / RPW;              // 18432
    const int grid   = waves / WPB;               // 4608 blocks of 256 threads

    dim3 block(64 * WPB);
    symctl_kernel<<<grid, block, 0, stream>>>(x, s, w, out);
}